// Round 1
// baseline (425.116 us; speedup 1.0000x reference)
//
#include <hip/hip_runtime.h>

// TimeGraphNet: per-row conv/pool chain [64,1024,1200] -> feat[64,1024],
// then tiny classifier + softmax -> [64,3].
//
// Reference chain per row x[0..1199]:
//   y1[j] = relu(b1 + sum_{k=0..9} w1[k]*X(8j+k-1)), j=0..149  (zero pad)
//   p1[m] = max(y1[5m..5m+4]), m=0..29
//   y2[j] = relu(b2 + sum_{k=0..2} w2[k]*p1[3j+k]), j=0..9
//   p2[0]=max(y2[0],y2[1]); p2[1]=max(y2[2..4]); p2[2]=max(y2[5..7]); p2[3]=max(y2[8],y2[9])
//     (maxpool k=3,s=3,pad=1 with -inf padding)
//   feat  = relu(b3 + sum_{k=0..3} w3[k]*p2[k])
// logits = feat @ cls_w.T + cls_b ; softmax over 3 classes.

#define T_LEN 1200
#define NROWS (64 * 1024)

__global__ __launch_bounds__(256) void row_chain_kernel(
    const float* __restrict__ input,
    const float* __restrict__ w1, const float* __restrict__ b1,
    const float* __restrict__ w2, const float* __restrict__ b2,
    const float* __restrict__ w3, const float* __restrict__ b3,
    float* __restrict__ feat)
{
    __shared__ __align__(16) float xs[T_LEN];
    __shared__ float y1[152];
    __shared__ float p1[32];
    __shared__ float y2[10];

    const int tid = threadIdx.x;
    const size_t row = blockIdx.x;

    // Stage row into LDS: 300 float4 loads, coalesced.
    const float4* src = (const float4*)(input + row * T_LEN);
    float4* dst = (float4*)xs;
    for (int i = tid; i < T_LEN / 4; i += 256) {
        dst[i] = src[i];
    }
    __syncthreads();

    // conv1: K=10, stride=8, pad=1 -> 150 outputs, relu.
    if (tid < 150) {
        float acc = b1[0];
        const int base = tid * 8 - 1;
        #pragma unroll
        for (int k = 0; k < 10; ++k) {
            const int idx = base + k;
            const float v = (idx >= 0 && idx < T_LEN) ? xs[idx] : 0.0f;
            acc = fmaf(w1[k], v, acc);
        }
        y1[tid] = fmaxf(acc, 0.0f);
    }
    __syncthreads();

    // maxpool k=5, s=5: 150 -> 30. (relu redundant: inputs >= 0)
    if (tid < 30) {
        float m = y1[tid * 5];
        #pragma unroll
        for (int k = 1; k < 5; ++k) m = fmaxf(m, y1[tid * 5 + k]);
        p1[tid] = m;
    }
    __syncthreads();

    // conv2: K=3, stride=3 -> 10 outputs, relu.
    if (tid < 10) {
        float acc = b2[0];
        #pragma unroll
        for (int k = 0; k < 3; ++k) acc = fmaf(w2[k], p1[tid * 3 + k], acc);
        y2[tid] = fmaxf(acc, 0.0f);
    }
    __syncthreads();

    // maxpool k=3, s=3, pad=1 (-inf) -> 4; conv3 K=4 -> 1; relu.
    if (tid == 0) {
        const float q0 = fmaxf(y2[0], y2[1]);
        const float q1 = fmaxf(fmaxf(y2[2], y2[3]), y2[4]);
        const float q2 = fmaxf(fmaxf(y2[5], y2[6]), y2[7]);
        const float q3 = fmaxf(y2[8], y2[9]);
        float f = b3[0];
        f = fmaf(w3[0], q0, f);
        f = fmaf(w3[1], q1, f);
        f = fmaf(w3[2], q2, f);
        f = fmaf(w3[3], q3, f);
        feat[row] = fmaxf(f, 0.0f);
    }
}

// One block per batch element: logits = feat[b,:] . cls_w[c,:] + cls_b[c],
// softmax over c in {0,1,2}.
__global__ __launch_bounds__(256) void classifier_kernel(
    const float* __restrict__ feat,
    const float* __restrict__ cls_w,
    const float* __restrict__ cls_b,
    float* __restrict__ out)
{
    const int b = blockIdx.x;
    const int tid = threadIdx.x;

    float s0 = 0.0f, s1 = 0.0f, s2 = 0.0f;
    for (int n = tid; n < 1024; n += 256) {
        const float f = feat[b * 1024 + n];
        s0 = fmaf(f, cls_w[n], s0);
        s1 = fmaf(f, cls_w[1024 + n], s1);
        s2 = fmaf(f, cls_w[2048 + n], s2);
    }
    // Wave (64-lane) butterfly reduce.
    #pragma unroll
    for (int off = 32; off > 0; off >>= 1) {
        s0 += __shfl_down(s0, off, 64);
        s1 += __shfl_down(s1, off, 64);
        s2 += __shfl_down(s2, off, 64);
    }
    __shared__ float red[3][4];
    const int wave = tid >> 6;
    if ((tid & 63) == 0) {
        red[0][wave] = s0;
        red[1][wave] = s1;
        red[2][wave] = s2;
    }
    __syncthreads();
    if (tid == 0) {
        const float l0 = red[0][0] + red[0][1] + red[0][2] + red[0][3] + cls_b[0];
        const float l1 = red[1][0] + red[1][1] + red[1][2] + red[1][3] + cls_b[1];
        const float l2 = red[2][0] + red[2][1] + red[2][2] + red[2][3] + cls_b[2];
        const float m = fmaxf(l0, fmaxf(l1, l2));
        const float e0 = expf(l0 - m);
        const float e1 = expf(l1 - m);
        const float e2 = expf(l2 - m);
        const float inv = 1.0f / (e0 + e1 + e2);
        out[b * 3 + 0] = e0 * inv;
        out[b * 3 + 1] = e1 * inv;
        out[b * 3 + 2] = e2 * inv;
    }
}

extern "C" void kernel_launch(void* const* d_in, const int* in_sizes, int n_in,
                              void* d_out, int out_size, void* d_ws, size_t ws_size,
                              hipStream_t stream) {
    const float* input   = (const float*)d_in[0];
    const float* conv1_w = (const float*)d_in[1];
    const float* conv1_b = (const float*)d_in[2];
    const float* conv2_w = (const float*)d_in[3];
    const float* conv2_b = (const float*)d_in[4];
    const float* conv3_w = (const float*)d_in[5];
    const float* conv3_b = (const float*)d_in[6];
    // d_in[7..10]: gcn weights/biases — dead code in the reference.
    const float* cls_w   = (const float*)d_in[11];
    const float* cls_b   = (const float*)d_in[12];

    float* feat = (float*)d_ws;  // 65536 floats = 256 KB scratch
    float* out  = (float*)d_out; // 64*3 fp32

    row_chain_kernel<<<NROWS, 256, 0, stream>>>(
        input, conv1_w, conv1_b, conv2_w, conv2_b, conv3_w, conv3_b, feat);
    classifier_kernel<<<64, 256, 0, stream>>>(feat, cls_w, cls_b, out);
}